// Round 7
// baseline (6690.786 us; speedup 1.0000x reference)
//
#include <hip/hip_runtime.h>
#include <math.h>

#define PI_D 3.14159265358979323846

// ---------------- workspace layout (float units) ----------------
#define IMG224 50176
#define IMG112 12544
// factorized DFT tables: per (N,dir): [W1:N1*N1 | W2:N2*N2 | TW:N2*N1] float2
static const size_t OFF_FT224F = 0;        // 676 c -> pad 2048 f
static const size_t OFF_FT224I = 2048;
static const size_t OFF_FT112F = 4096;
static const size_t OFF_FT112I = 6144;
static const size_t OFF_F56I  = 250880;    // 6272 (dense 56 inverse)
static const size_t OFF_PSI   = 257152;    // 16*50176
static const size_t OFF_PHI0  = 1059968;
static const size_t OFF_PHI1  = 1110144;
static const size_t OFF_GK    = 1122688;   // 3888 keys
static const size_t OFF_XH    = 1126784;   // 4816896
static const size_t OFF_POOL  = 5943680;
// arena: A0, A1, A23 = 9633792 floats each -> total 34.8M floats = 139 MB (< known-good 149 MB)

// ---------------- helpers ----------------
__device__ inline unsigned fkey(float v) {
    int b = __float_as_int(v);
    return (b >= 0) ? ((unsigned)b | 0x80000000u) : ~(unsigned)b;
}
__device__ inline float funkey(unsigned u) {
    int b = (u & 0x80000000u) ? (int)(u & 0x7fffffffu) : (int)~u;
    return __int_as_float(b);
}
__device__ inline void cmac(float2& a, float2 z, float2 w) {
    a.x += z.x * w.x - z.y * w.y;
    a.y += z.x * w.y + z.y * w.x;
}

// ---------------- table builders ----------------
__global__ void k_dft(float2* out, int n, double sign, double scale) {
    int i = blockIdx.x * blockDim.x + threadIdx.x;
    if (i >= n * n) return;
    int c = i / n, k = i % n;
    int m = (c * k) % n;
    double ang = sign * 2.0 * PI_D * (double)m / (double)n;
    out[i] = make_float2((float)(scale * cos(ang)), (float)(scale * sin(ang)));
}

__global__ void k_fact(float2* o, int N1, int N2, double sign, double scale) {
    int total = N1 * N1 + N2 * N2 + N2 * N1;
    int N = N1 * N2;
    for (int i = blockIdx.x * blockDim.x + threadIdx.x; i < total; i += blockDim.x * gridDim.x) {
        double ang; double sc = 1.0;
        if (i < N1 * N1) {
            int n1 = i / N1, k1 = i % N1;
            ang = sign * 2.0 * PI_D * (double)((n1 * k1) % N1) / (double)N1;
        } else if (i < N1 * N1 + N2 * N2) {
            int j = i - N1 * N1; int n2 = j / N2, k2 = j % N2;
            ang = sign * 2.0 * PI_D * (double)((n2 * k2) % N2) / (double)N2;
            sc = scale;
        } else {
            int j = i - N1 * N1 - N2 * N2; int n2 = j / N1, k1 = j % N1;
            ang = sign * 2.0 * PI_D * (double)((n2 * k1) % N) / (double)N;
        }
        o[i] = make_float2((float)(sc * cos(ang)), (float)(sc * sin(ang)));
    }
}

__global__ void k_psi(float* out) {
    int i = blockIdx.x * blockDim.x + threadIdx.x;
    if (i >= 16 * IMG224) return;
    int jl = i / IMG224, p = i % IMG224;
    int r = p / 224, c = p % 224;
    int j = jl >> 3, l = jl & 7;
    double fr = (r < 112) ? (double)r : (double)(r - 224);
    double fc = (c < 112) ? (double)c : (double)(c - 224);
    double wx = 2.0 * PI_D * fr / 224.0;
    double wy = 2.0 * PI_D * fc / 224.0;
    double theta = (double)l * PI_D / 8.0;
    double xi = (3.0 * PI_D / 4.0) / (double)(1 << j);
    double sg = 0.8 * (double)(1 << j);
    double ct = cos(theta), st = sin(theta);
    double u = ct * wx + st * wy;
    double v = -st * wx + ct * wy;
    double vs = v / 0.5;
    double s2 = 0.5 * sg * sg;
    double gab = exp(-s2 * ((u - xi) * (u - xi) + vs * vs));
    double gau = exp(-s2 * (u * u + vs * vs));
    double kap = exp(-s2 * xi * xi);
    out[i] = (float)(gab - kap * gau);
}

__global__ void k_phi(float* phi0, float* phi1) {
    int i = blockIdx.x * blockDim.x + threadIdx.x;
    const double sp = 1.6;
    const double s2 = 0.5 * sp * sp;
    if (i < IMG224) {
        int r = i / 224, c = i % 224;
        double fr = (r < 112) ? (double)r : (double)(r - 224);
        double fc = (c < 112) ? (double)c : (double)(c - 224);
        double wx = 2.0 * PI_D * fr / 224.0;
        double wy = 2.0 * PI_D * fc / 224.0;
        phi0[i] = (float)exp(-s2 * (wx * wx + wy * wy));
    } else if (i < IMG224 + IMG112) {
        int p = i - IMG224, a = p / 112, b = p % 112;
        double sum = 0.0;
        for (int ii = 0; ii < 2; ++ii)
            for (int jj = 0; jj < 2; ++jj) {
                int r = a + 112 * ii, c = b + 112 * jj;
                double fr = (r < 112) ? (double)r : (double)(r - 224);
                double fc = (c < 112) ? (double)c : (double)(c - 224);
                double wx = 2.0 * PI_D * fr / 224.0;
                double wy = 2.0 * PI_D * fc / 224.0;
                sum += exp(-s2 * (wx * wx + wy * wy));
            }
        phi1[p] = (float)(0.25 * sum);
    }
}

__global__ void k_zero(unsigned* gk, int n) {
    int i = blockIdx.x * blockDim.x + threadIdx.x;
    if (i < n) gk[i] = 0u;
}

// ---------------- rk: row pass, two-stage (N=N1*N2), fused in LDS ----------------
// swzImg>0: XCD-locality swizzle (img = bx % swzImg): all filter-variants of one
// image share bx%8 -> one XCD L2. gIn = img*inStride + inOff (V1 is pair-interleaved).
template<int N1, int N2, int TA, int FOLD, int BS, bool REAL>
__global__ __launch_bounds__(BS) void rk(
    const void* __restrict__ inBase, int inShift,
    const float* __restrict__ fltBase, int fltMask,
    const float2* __restrict__ FT, float2* __restrict__ out,
    int swzImg, int inStride, int inOff)
{
    constexpr int N = N1 * N2;
    constexpr int NIN = N * FOLD;
    constexpr int ZS = N + 2;
    constexpr int TS = N2 * (N1 + 1);
    __shared__ float2 Z[TA * ZS];
    __shared__ float2 T[TA * TS];
    const float2* W1 = FT;
    const float2* W2 = FT + N1 * N1;
    const float2* TW = FT + N1 * N1 + N2 * N2;
    const int bx = blockIdx.x, a0 = blockIdx.y * TA, t = threadIdx.x;
    int gIn, gFlt, gOut;
    if (swzImg > 0) {
        int img = bx % swzImg, sub = bx / swzImg;
        gIn = img * inStride + inOff; gFlt = sub; gOut = img * (gridDim.x / swzImg) + sub;
    } else {
        gIn = bx >> inShift; gFlt = bx & fltMask; gOut = bx;
    }

    if (REAL) {
        const float* in = (const float*)inBase + (size_t)gIn * N * N;
        for (int r = 0; r < TA; ++r)
            for (int b = t; b < N; b += BS)
                Z[r * ZS + b] = make_float2(in[(size_t)(a0 + r) * N + b], 0.f);
    } else {
        const float2* in = (const float2*)inBase + (size_t)gIn * (NIN * NIN);
        const float* flt = fltBase + (size_t)gFlt * (NIN * NIN);
        const float s = 1.0f / (float)(FOLD * FOLD);
        for (int r = 0; r < TA; ++r) {
            int a = a0 + r;
            for (int b = t; b < N; b += BS) {
                float re = 0.f, im = 0.f;
#pragma unroll
                for (int i = 0; i < FOLD; ++i)
#pragma unroll
                    for (int j = 0; j < FOLD; ++j) {
                        int idx = (a + N * i) * NIN + (b + N * j);
                        float2 v = in[idx];
                        float f = flt[idx];
                        re += v.x * f; im += v.y * f;
                    }
                Z[r * ZS + b] = make_float2(re * s, im * s);
            }
        }
    }
    __syncthreads();
    // pass 1: (r,n2) -> T[r][n2][k1]
    for (int idx = t; idx < TA * N2; idx += BS) {
        int r = idx / N2, n2 = idx % N2;
        float2 acc[N1];
#pragma unroll
        for (int k1 = 0; k1 < N1; ++k1) acc[k1] = make_float2(0.f, 0.f);
        for (int n1 = 0; n1 < N1; ++n1) {
            float2 zv = Z[r * ZS + n1 * N2 + n2];
#pragma unroll
            for (int k1 = 0; k1 < N1; ++k1) cmac(acc[k1], zv, W1[n1 * N1 + k1]);
        }
#pragma unroll
        for (int k1 = 0; k1 < N1; ++k1) {
            float2 tw = TW[n2 * N1 + k1];
            float2 a2;
            a2.x = acc[k1].x * tw.x - acc[k1].y * tw.y;
            a2.y = acc[k1].x * tw.y + acc[k1].y * tw.x;
            T[r * TS + n2 * (N1 + 1) + k1] = a2;
        }
    }
    __syncthreads();
    // pass 2: (r,k1) -> Z[r][k1+N1*k2]
    for (int idx = t; idx < TA * N1; idx += BS) {
        int r = idx / N1, k1 = idx % N1;
        float2 acc[N2];
#pragma unroll
        for (int k2 = 0; k2 < N2; ++k2) acc[k2] = make_float2(0.f, 0.f);
        for (int n2 = 0; n2 < N2; ++n2) {
            float2 tv = T[r * TS + n2 * (N1 + 1) + k1];
#pragma unroll
            for (int k2 = 0; k2 < N2; ++k2) cmac(acc[k2], tv, W2[n2 * N2 + k2]);
        }
#pragma unroll
        for (int k2 = 0; k2 < N2; ++k2) Z[r * ZS + k1 + N1 * k2] = acc[k2];
    }
    __syncthreads();
    for (int r = 0; r < TA; ++r) {
        float2* o = out + ((size_t)gOut * N + (a0 + r)) * N;
        for (int b = t; b < N; b += BS) o[b] = Z[r * ZS + b];
    }
}

// ---------------- ck1/ck2: split column pass (224-res; SPLIT slices) ----------------
template<int N1, int N2, int SPLIT, int BS>
__global__ __launch_bounds__(BS) void ck1(
    const float2* __restrict__ in, const float2* __restrict__ FT, float2* __restrict__ out)
{
    constexpr int N = N1 * N2;
    constexpr int NC = N / SPLIT;
    const float2* W1 = FT;
    const float2* TW = FT + N1 * N1 + N2 * N2;
    const int g = blockIdx.x / SPLIT, half = blockIdx.x % SPLIT;
    const int n2 = blockIdx.y, t = threadIdx.x;
    if (2 * t >= NC) return;
    const int b0 = 2 * t + half * NC;
    const float2* I = in + (size_t)g * N * N;
    float2 acc[N1][2];
#pragma unroll
    for (int k1 = 0; k1 < N1; ++k1) { acc[k1][0] = make_float2(0.f, 0.f); acc[k1][1] = make_float2(0.f, 0.f); }
    for (int n1 = 0; n1 < N1; ++n1) {
        float4 v = *reinterpret_cast<const float4*>(&I[(size_t)(n1 * N2 + n2) * N + b0]);
        float2 v0 = make_float2(v.x, v.y), v1 = make_float2(v.z, v.w);
#pragma unroll
        for (int k1 = 0; k1 < N1; ++k1) {
            float2 w = W1[n1 * N1 + k1];
            cmac(acc[k1][0], v0, w);
            cmac(acc[k1][1], v1, w);
        }
    }
#pragma unroll
    for (int k1 = 0; k1 < N1; ++k1) {
        float2 tw = TW[n2 * N1 + k1];
        float2 a0, a1;
        a0.x = acc[k1][0].x * tw.x - acc[k1][0].y * tw.y;
        a0.y = acc[k1][0].x * tw.y + acc[k1][0].y * tw.x;
        a1.x = acc[k1][1].x * tw.x - acc[k1][1].y * tw.y;
        a1.y = acc[k1][1].x * tw.y + acc[k1][1].y * tw.x;
        *reinterpret_cast<float4*>(&out[((size_t)g * N + (k1 * N2 + n2)) * N + b0]) =
            make_float4(a0.x, a0.y, a1.x, a1.y);
    }
}

template<int N1, int N2, int SPLIT, int MODE, int BS>
__global__ __launch_bounds__(BS) void ck2(
    const float2* __restrict__ in, const float2* __restrict__ FT,
    float2* __restrict__ outc, float* __restrict__ outr)
{
    constexpr int N = N1 * N2;
    constexpr int NC = N / SPLIT;
    const float2* W2 = FT + N1 * N1;
    const int g = blockIdx.x / SPLIT, half = blockIdx.x % SPLIT;
    const int k1 = blockIdx.y, t = threadIdx.x;
    if (2 * t >= NC) return;
    const int b0 = 2 * t + half * NC;
    const float2* I = in + (size_t)g * N * N;
    float2 acc[N2][2];
#pragma unroll
    for (int k2 = 0; k2 < N2; ++k2) { acc[k2][0] = make_float2(0.f, 0.f); acc[k2][1] = make_float2(0.f, 0.f); }
    for (int n2 = 0; n2 < N2; ++n2) {
        float4 v = *reinterpret_cast<const float4*>(&I[(size_t)(k1 * N2 + n2) * N + b0]);
        float2 v0 = make_float2(v.x, v.y), v1 = make_float2(v.z, v.w);
#pragma unroll
        for (int k2 = 0; k2 < N2; ++k2) {
            float2 w = W2[n2 * N2 + k2];
            cmac(acc[k2][0], v0, w);
            cmac(acc[k2][1], v1, w);
        }
    }
    if (MODE == 0) {
#pragma unroll
        for (int k2 = 0; k2 < N2; ++k2)
            *reinterpret_cast<float4*>(&outc[((size_t)g * N + (k1 + N1 * k2)) * N + b0]) =
                make_float4(acc[k2][0].x, acc[k2][0].y, acc[k2][1].x, acc[k2][1].y);
    } else {
#pragma unroll
        for (int k2 = 0; k2 < N2; ++k2) {
            size_t o = ((size_t)g * N + (k1 + N1 * k2)) * N + b0;
            outr[o]     = sqrtf(acc[k2][0].x * acc[k2][0].x + acc[k2][0].y * acc[k2][0].y);
            outr[o + 1] = sqrtf(acc[k2][1].x * acc[k2][1].x + acc[k2][1].y * acc[k2][1].y);
        }
    }
}

// ---------------- ckf: fused two-stage column pass (112-res only; 2688-block grid) ----
template<int N1, int N2, int TB, int MODE, int BS>
__global__ __launch_bounds__(BS) void ckf(
    const float2* __restrict__ in, const float2* __restrict__ FT,
    float2* __restrict__ outc, float* __restrict__ outr)
{
    constexpr int N = N1 * N2;
    constexpr int TS = TB + 1;
    __shared__ float2 A[N * TS];
    const float2* W1 = FT;
    const float2* W2 = FT + N1 * N1;
    const float2* TW = FT + N1 * N1 + N2 * N2;
    const int g = blockIdx.x, col0 = blockIdx.y * TB, t = threadIdx.x;
    const float2* I = in + (size_t)g * N * N;
    for (int idx = t; idx < N * TB; idx += BS) {
        int r = idx / TB, b = idx % TB;
        A[r * TS + b] = I[(size_t)r * N + col0 + b];
    }
    __syncthreads();
    for (int idx = t; idx < N2 * TB; idx += BS) {
        int n2 = idx / TB, b = idx % TB;
        float2 v[N1];
#pragma unroll
        for (int n1 = 0; n1 < N1; ++n1) v[n1] = A[(n1 * N2 + n2) * TS + b];
#pragma unroll
        for (int k1 = 0; k1 < N1; ++k1) {
            float2 acc = make_float2(0.f, 0.f);
#pragma unroll
            for (int n1 = 0; n1 < N1; ++n1) cmac(acc, v[n1], W1[n1 * N1 + k1]);
            float2 tw = TW[n2 * N1 + k1];
            float2 o;
            o.x = acc.x * tw.x - acc.y * tw.y;
            o.y = acc.x * tw.y + acc.y * tw.x;
            A[(k1 * N2 + n2) * TS + b] = o;
        }
    }
    __syncthreads();
    for (int idx = t; idx < N1 * TB; idx += BS) {
        int k1 = idx / TB, b = idx % TB;
        float2 v[N2];
#pragma unroll
        for (int n2 = 0; n2 < N2; ++n2) v[n2] = A[(k1 * N2 + n2) * TS + b];
#pragma unroll
        for (int k2 = 0; k2 < N2; ++k2) {
            float2 acc = make_float2(0.f, 0.f);
#pragma unroll
            for (int n2 = 0; n2 < N2; ++n2) cmac(acc, v[n2], W2[n2 * N2 + k2]);
            size_t o = ((size_t)g * N + (k1 + N1 * k2)) * N + col0 + b;
            if (MODE == 0) outc[o] = acc;
            else outr[o] = sqrtf(acc.x * acc.x + acc.y * acc.y);
        }
    }
}

// ---------------- s56: fused fold*phi -> ifft2(56) -> real -> max -> atomicMax ----
template<int FOLD, int BS>
__global__ __launch_bounds__(BS) void s56(
    const float2* __restrict__ in, const float* __restrict__ flt,
    const float2* __restrict__ W, unsigned* __restrict__ gk,
    int slotBase, int slotShift, int slotMask)
{
    constexpr int N = 56, NIN = 56 * FOLD, ZS = 57;
    __shared__ float2 Z[N * ZS];
    __shared__ float2 T[N * ZS];
    __shared__ float red[BS / 64];
    const int g = blockIdx.x, t = threadIdx.x;
    const float2* I = in + (size_t)g * NIN * NIN;
    const float s = 1.0f / (float)(FOLD * FOLD);
    for (int idx = t; idx < N * N; idx += BS) {
        int r = idx / N, b = idx % N;
        float re = 0.f, im = 0.f;
#pragma unroll
        for (int i = 0; i < FOLD; ++i)
#pragma unroll
            for (int j = 0; j < FOLD; ++j) {
                int p = (r + N * i) * NIN + (b + N * j);
                float2 v = I[p];
                float f = flt[p];
                re += v.x * f; im += v.y * f;
            }
        Z[r * ZS + b] = make_float2(re * s, im * s);
    }
    __syncthreads();
    // row DFT: T[r][k] = sum_b Z[r][b] * W[b][k]
    for (int idx = t; idx < N * N; idx += BS) {
        int r = idx / N, k = idx % N;
        float2 acc = make_float2(0.f, 0.f);
        for (int b = 0; b < N; ++b) cmac(acc, Z[r * ZS + b], W[b * N + k]);
        T[r * ZS + k] = acc;
    }
    __syncthreads();
    // col DFT (real part only) + max
    float m = -INFINITY;
    for (int idx = t; idx < N * N; idx += BS) {
        int k = idx / N, b = idx % N;
        float re = 0.f;
        for (int a = 0; a < N; ++a) {
            float2 w = W[a * N + k];
            float2 v = T[a * ZS + b];
            re += w.x * v.x - w.y * v.y;
        }
        m = fmaxf(m, re);
    }
    for (int off = 32; off > 0; off >>= 1) m = fmaxf(m, __shfl_down(m, off, 64));
    if ((t & 63) == 0) red[t >> 6] = m;
    __syncthreads();
    if (t == 0) {
        for (int w = 1; w < BS / 64; ++w) m = fmaxf(m, red[w]);
        int slot = slotBase + ((g >> slotShift) * 81) + (g & slotMask);
        atomicMax(&gk[slot], fkey(m));
    }
}

// ---------------- classifier head ----------------
__global__ void k_linear(const unsigned* __restrict__ gk, const float* __restrict__ Wl,
                         const float* __restrict__ bl, float* __restrict__ out)
{
    int i = blockIdx.x * blockDim.x + threadIdx.x;
    if (i >= 16 * 1000) return;
    int b = i / 1000, o = i % 1000;
    float s = bl[o];
    for (int f = 0; f < 243; ++f)
        s += funkey(gk[b * 243 + f]) * Wl[o * 243 + f];
    out[i] = s;
}

// ---------------- launch ----------------
extern "C" void kernel_launch(void* const* d_in, const int* in_sizes, int n_in,
                              void* d_out, int out_size, void* d_ws, size_t ws_size,
                              hipStream_t stream)
{
    const float* x  = (const float*)d_in[0];
    const float* Wl = (const float*)d_in[1];
    const float* bl = (const float*)d_in[2];
    float* out = (float*)d_out;
    float* ws = (float*)d_ws;

    float2* FT224F = (float2*)(ws + OFF_FT224F);
    float2* FT224I = (float2*)(ws + OFF_FT224I);
    float2* FT112F = (float2*)(ws + OFF_FT112F);
    float2* FT112I = (float2*)(ws + OFF_FT112I);
    float2* F56I  = (float2*)(ws + OFF_F56I);
    float* PSI0 = ws + OFF_PSI;
    float* PSI1 = ws + OFF_PSI + 8 * IMG224;
    float* PHI0 = ws + OFF_PHI0;
    float* PHI1 = ws + OFF_PHI1;
    unsigned* GK = (unsigned*)(ws + OFF_GK);
    float2* XH  = (float2*)(ws + OFF_XH);
    float* A0  = ws + OFF_POOL;          // 9633792 floats
    float* A1  = A0 + 9633792;           // 9633792
    float* A23 = A1 + 9633792;           // 9633792

    // tables
    k_fact<<<4, 256, 0, stream>>>(FT224F, 16, 14, -1.0, 1.0);
    k_fact<<<4, 256, 0, stream>>>(FT224I, 16, 14,  1.0, 1.0 / 224.0);
    k_fact<<<4, 256, 0, stream>>>(FT112F, 16, 7,  -1.0, 1.0);
    k_fact<<<4, 256, 0, stream>>>(FT112I, 16, 7,   1.0, 1.0 / 112.0);
    k_dft<<<(56*56 + 255) / 256, 256, 0, stream>>>(F56I, 56, 1.0, 1.0 / 56.0);
    k_psi<<<(16 * IMG224 + 255) / 256, 256, 0, stream>>>(ws + OFF_PSI);
    k_phi<<<(IMG224 + IMG112 + 255) / 256, 256, 0, stream>>>(PHI0, PHI1);
    k_zero<<<(3888 + 255) / 256, 256, 0, stream>>>(GK, 3888);

    // ---- fft2(x) -> XH ----
    rk<16, 14, 8, 1, 128, true><<<dim3(48, 28), 128, 0, stream>>>(x, 0, nullptr, 0, FT224F, (float2*)A0, 0, 0, 0);
    ck1<16, 14, 2, 64><<<dim3(96, 14), 64, 0, stream>>>((float2*)A0, FT224F, (float2*)A1);
    ck2<16, 14, 2, 0, 64><<<dim3(96, 16), 64, 0, stream>>>((float2*)A1, FT224F, XH, nullptr);

    // ---- s0 -> GK slot img*81+0 ----
    s56<4, 256><<<48, 256, 0, stream>>>(XH, PHI0, F56I, GK, 0, 0, 0);

    // ---- pair-batched first order j1=0 (+ second order), c = pair index ----
    // batched group index g = img*2 + lc, l1 = 2c + lc
    for (int c = 0; c < 4; ++c) {
        // A: ifft rows of xh*psi0[l1] -> A0 (96 groups)
        rk<16, 14, 8, 1, 128, false><<<dim3(96, 28), 128, 0, stream>>>(
            XH, 1, PSI0 + (size_t)(2 * c) * IMG224, 1, FT224I, (float2*)A0, 0, 0, 0);
        // B: ifft cols + |.| -> A23 (real u1, 96x50176)
        ck1<16, 14, 2, 64><<<dim3(192, 14), 64, 0, stream>>>((float2*)A0, FT224I, (float2*)A1);
        ck2<16, 14, 2, 1, 64><<<dim3(192, 16), 64, 0, stream>>>((float2*)A1, FT224I, nullptr, A23);
        // C: fft rows of u1 (real) -> A0
        rk<16, 14, 8, 1, 128, true><<<dim3(96, 28), 128, 0, stream>>>(A23, 0, nullptr, 0, FT224F, (float2*)A0, 0, 0, 0);
        // D: fft cols -> V1 (A0; A0 free after ck1)
        ck1<16, 14, 2, 64><<<dim3(192, 14), 64, 0, stream>>>((float2*)A0, FT224F, (float2*)A1);
        ck2<16, 14, 2, 0, 64><<<dim3(192, 16), 64, 0, stream>>>((float2*)A1, FT224F, (float2*)A0, nullptr);
        // E: s1 -> GK slot img*81 + 1 + 2c + lc
        s56<4, 256><<<96, 256, 0, stream>>>((float2*)A0, PHI0, F56I, GK, 1 + 2 * c, 1, 1);
        // second order per l1 in pair (V1 stays in A0)
        for (int lc = 0; lc < 2; ++lc) {
            int l1 = 2 * c + lc;
            // F: ifft112 rows of fold(V1*psi1[l2],2) [XCD swizzle] -> A1 (384 groups)
            rk<16, 7, 16, 2, 128, false><<<dim3(384, 7), 128, 0, stream>>>(
                (float2*)A0, 0, PSI1, 7, FT112I, (float2*)A1, 48, 2, lc);
            // G: ifft112 cols + |.| -> A23 (real u2)
            ckf<16, 7, 16, 1, 64><<<dim3(384, 7), 64, 0, stream>>>((float2*)A1, FT112I, nullptr, A23);
            // H: fft112 rows of u2 (real) -> A1
            rk<16, 7, 16, 1, 128, true><<<dim3(384, 7), 128, 0, stream>>>(A23, 0, nullptr, 0, FT112F, (float2*)A1, 0, 0, 0);
            // I: fft112 cols -> u2h -> A23
            ckf<16, 7, 16, 0, 64><<<dim3(384, 7), 64, 0, stream>>>((float2*)A1, FT112F, (float2*)A23, nullptr);
            // JK: s2 -> GK slot img*81 + 17 + 8*l1 + l2
            s56<2, 256><<<384, 256, 0, stream>>>((float2*)A23, PHI1, F56I, GK, 17 + 8 * l1, 3, 7);
        }
    }

    // ---- first order j1=1 (8 orientations, g = img*8+l) ----
    rk<16, 7, 16, 2, 128, false><<<dim3(384, 7), 128, 0, stream>>>(XH, 0, PSI1, 7, FT112I, (float2*)A1, 48, 1, 0);
    ckf<16, 7, 16, 1, 64><<<dim3(384, 7), 64, 0, stream>>>((float2*)A1, FT112I, nullptr, A23);
    rk<16, 7, 16, 1, 128, true><<<dim3(384, 7), 128, 0, stream>>>(A23, 0, nullptr, 0, FT112F, (float2*)A1, 0, 0, 0);
    ckf<16, 7, 16, 0, 64><<<dim3(384, 7), 64, 0, stream>>>((float2*)A1, FT112F, (float2*)A23, nullptr);
    s56<2, 256><<<384, 256, 0, stream>>>((float2*)A23, PHI1, F56I, GK, 9, 3, 7);

    // head
    k_linear<<<(16000 + 255) / 256, 256, 0, stream>>>(GK, Wl, bl, out);
}

// Round 8
// 3580.585 us; speedup vs baseline: 1.8686x; 1.8686x over previous
//
#include <hip/hip_runtime.h>
#include <math.h>

#define PI_D 3.14159265358979323846

// ---------------- workspace layout (float units) ----------------
#define IMG224 50176
#define IMG112 12544
// factorized DFT tables: per (N,dir): [W1:N1*N1 | W2:N2*N2 | TW:N2*N1] float2
static const size_t OFF_FT224F = 0;
static const size_t OFF_FT224I = 2048;
static const size_t OFF_FT112F = 4096;
static const size_t OFF_FT112I = 6144;
static const size_t OFF_F56I  = 250880;    // 6272 (dense 56 inverse)
static const size_t OFF_PSI   = 257152;    // 16*50176
static const size_t OFF_PHI0  = 1059968;
static const size_t OFF_PHI1  = 1110144;
static const size_t OFF_GK    = 1122688;   // 3888 keys
static const size_t OFF_XH    = 1126784;   // 4816896
static const size_t OFF_POOL  = 5943680;
// arena: A0, A1, A23 = 9633792 floats each -> total ~139 MB (< known-good 149 MB)

// ---------------- helpers ----------------
__device__ inline unsigned fkey(float v) {
    int b = __float_as_int(v);
    return (b >= 0) ? ((unsigned)b | 0x80000000u) : ~(unsigned)b;
}
__device__ inline float funkey(unsigned u) {
    int b = (u & 0x80000000u) ? (int)(u & 0x7fffffffu) : (int)~u;
    return __int_as_float(b);
}
__device__ inline void cmac(float2& a, float2 z, float2 w) {
    a.x += z.x * w.x - z.y * w.y;
    a.y += z.x * w.y + z.y * w.x;
}

// ---------------- table builders ----------------
__global__ void k_dft(float2* out, int n, double sign, double scale) {
    int i = blockIdx.x * blockDim.x + threadIdx.x;
    if (i >= n * n) return;
    int c = i / n, k = i % n;
    int m = (c * k) % n;
    double ang = sign * 2.0 * PI_D * (double)m / (double)n;
    out[i] = make_float2((float)(scale * cos(ang)), (float)(scale * sin(ang)));
}

__global__ void k_fact(float2* o, int N1, int N2, double sign, double scale) {
    int total = N1 * N1 + N2 * N2 + N2 * N1;
    int N = N1 * N2;
    for (int i = blockIdx.x * blockDim.x + threadIdx.x; i < total; i += blockDim.x * gridDim.x) {
        double ang; double sc = 1.0;
        if (i < N1 * N1) {
            int n1 = i / N1, k1 = i % N1;
            ang = sign * 2.0 * PI_D * (double)((n1 * k1) % N1) / (double)N1;
        } else if (i < N1 * N1 + N2 * N2) {
            int j = i - N1 * N1; int n2 = j / N2, k2 = j % N2;
            ang = sign * 2.0 * PI_D * (double)((n2 * k2) % N2) / (double)N2;
            sc = scale;
        } else {
            int j = i - N1 * N1 - N2 * N2; int n2 = j / N1, k1 = j % N1;
            ang = sign * 2.0 * PI_D * (double)((n2 * k1) % N) / (double)N;
        }
        o[i] = make_float2((float)(sc * cos(ang)), (float)(sc * sin(ang)));
    }
}

__global__ void k_psi(float* out) {
    int i = blockIdx.x * blockDim.x + threadIdx.x;
    if (i >= 16 * IMG224) return;
    int jl = i / IMG224, p = i % IMG224;
    int r = p / 224, c = p % 224;
    int j = jl >> 3, l = jl & 7;
    double fr = (r < 112) ? (double)r : (double)(r - 224);
    double fc = (c < 112) ? (double)c : (double)(c - 224);
    double wx = 2.0 * PI_D * fr / 224.0;
    double wy = 2.0 * PI_D * fc / 224.0;
    double theta = (double)l * PI_D / 8.0;
    double xi = (3.0 * PI_D / 4.0) / (double)(1 << j);
    double sg = 0.8 * (double)(1 << j);
    double ct = cos(theta), st = sin(theta);
    double u = ct * wx + st * wy;
    double v = -st * wx + ct * wy;
    double vs = v / 0.5;
    double s2 = 0.5 * sg * sg;
    double gab = exp(-s2 * ((u - xi) * (u - xi) + vs * vs));
    double gau = exp(-s2 * (u * u + vs * vs));
    double kap = exp(-s2 * xi * xi);
    out[i] = (float)(gab - kap * gau);
}

__global__ void k_phi(float* phi0, float* phi1) {
    int i = blockIdx.x * blockDim.x + threadIdx.x;
    const double sp = 1.6;
    const double s2 = 0.5 * sp * sp;
    if (i < IMG224) {
        int r = i / 224, c = i % 224;
        double fr = (r < 112) ? (double)r : (double)(r - 224);
        double fc = (c < 112) ? (double)c : (double)(c - 224);
        double wx = 2.0 * PI_D * fr / 224.0;
        double wy = 2.0 * PI_D * fc / 224.0;
        phi0[i] = (float)exp(-s2 * (wx * wx + wy * wy));
    } else if (i < IMG224 + IMG112) {
        int p = i - IMG224, a = p / 112, b = p % 112;
        double sum = 0.0;
        for (int ii = 0; ii < 2; ++ii)
            for (int jj = 0; jj < 2; ++jj) {
                int r = a + 112 * ii, c = b + 112 * jj;
                double fr = (r < 112) ? (double)r : (double)(r - 224);
                double fc = (c < 112) ? (double)c : (double)(c - 224);
                double wx = 2.0 * PI_D * fr / 224.0;
                double wy = 2.0 * PI_D * fc / 224.0;
                sum += exp(-s2 * (wx * wx + wy * wy));
            }
        phi1[p] = (float)(0.25 * sum);
    }
}

__global__ void k_zero(unsigned* gk, int n) {
    int i = blockIdx.x * blockDim.x + threadIdx.x;
    if (i < n) gk[i] = 0u;
}

// ---------------- rk: row pass, two-stage (N=N1*N2), fused in LDS ----------------
// T transposed [n2][N1+1] (bank-conflict fix, R5-measured). swzImg>0: XCD swizzle
// (img = bx % swzImg -> all filter-variants of an image on one XCD's L2; R6: FETCH 76->16MB).
template<int N1, int N2, int TA, int FOLD, int BS, bool REAL>
__global__ __launch_bounds__(BS) void rk(
    const void* __restrict__ inBase, int inShift,
    const float* __restrict__ fltBase, int fltMask,
    const float2* __restrict__ FT, float2* __restrict__ out,
    int swzImg, int inStride, int inOff)
{
    constexpr int N = N1 * N2;
    constexpr int NIN = N * FOLD;
    constexpr int ZS = N + 2;
    constexpr int TS = N2 * (N1 + 1);
    __shared__ float2 Z[TA * ZS];
    __shared__ float2 T[TA * TS];
    const float2* W1 = FT;
    const float2* W2 = FT + N1 * N1;
    const float2* TW = FT + N1 * N1 + N2 * N2;
    const int bx = blockIdx.x, a0 = blockIdx.y * TA, t = threadIdx.x;
    int gIn, gFlt, gOut;
    if (swzImg > 0) {
        int img = bx % swzImg, sub = bx / swzImg;
        gIn = img * inStride + inOff; gFlt = sub; gOut = img * (gridDim.x / swzImg) + sub;
    } else {
        gIn = bx >> inShift; gFlt = bx & fltMask; gOut = bx;
    }

    if (REAL) {
        const float* in = (const float*)inBase + (size_t)gIn * N * N;
        for (int r = 0; r < TA; ++r)
            for (int b = t; b < N; b += BS)
                Z[r * ZS + b] = make_float2(in[(size_t)(a0 + r) * N + b], 0.f);
    } else {
        const float2* in = (const float2*)inBase + (size_t)gIn * (NIN * NIN);
        const float* flt = fltBase + (size_t)gFlt * (NIN * NIN);
        const float s = 1.0f / (float)(FOLD * FOLD);
        for (int r = 0; r < TA; ++r) {
            int a = a0 + r;
            for (int b = t; b < N; b += BS) {
                float re = 0.f, im = 0.f;
#pragma unroll
                for (int i = 0; i < FOLD; ++i)
#pragma unroll
                    for (int j = 0; j < FOLD; ++j) {
                        int idx = (a + N * i) * NIN + (b + N * j);
                        float2 v = in[idx];
                        float f = flt[idx];
                        re += v.x * f; im += v.y * f;
                    }
                Z[r * ZS + b] = make_float2(re * s, im * s);
            }
        }
    }
    __syncthreads();
    // pass 1: (r,n2) -> T[r][n2][k1]
    for (int idx = t; idx < TA * N2; idx += BS) {
        int r = idx / N2, n2 = idx % N2;
        float2 acc[N1];
#pragma unroll
        for (int k1 = 0; k1 < N1; ++k1) acc[k1] = make_float2(0.f, 0.f);
        for (int n1 = 0; n1 < N1; ++n1) {
            float2 zv = Z[r * ZS + n1 * N2 + n2];
#pragma unroll
            for (int k1 = 0; k1 < N1; ++k1) cmac(acc[k1], zv, W1[n1 * N1 + k1]);
        }
#pragma unroll
        for (int k1 = 0; k1 < N1; ++k1) {
            float2 tw = TW[n2 * N1 + k1];
            float2 a2;
            a2.x = acc[k1].x * tw.x - acc[k1].y * tw.y;
            a2.y = acc[k1].x * tw.y + acc[k1].y * tw.x;
            T[r * TS + n2 * (N1 + 1) + k1] = a2;
        }
    }
    __syncthreads();
    // pass 2: (r,k1) -> Z[r][k1+N1*k2]
    for (int idx = t; idx < TA * N1; idx += BS) {
        int r = idx / N1, k1 = idx % N1;
        float2 acc[N2];
#pragma unroll
        for (int k2 = 0; k2 < N2; ++k2) acc[k2] = make_float2(0.f, 0.f);
        for (int n2 = 0; n2 < N2; ++n2) {
            float2 tv = T[r * TS + n2 * (N1 + 1) + k1];
#pragma unroll
            for (int k2 = 0; k2 < N2; ++k2) cmac(acc[k2], tv, W2[n2 * N2 + k2]);
        }
#pragma unroll
        for (int k2 = 0; k2 < N2; ++k2) Z[r * ZS + k1 + N1 * k2] = acc[k2];
    }
    __syncthreads();
    for (int r = 0; r < TA; ++r) {
        float2* o = out + ((size_t)gOut * N + (a0 + r)) * N;
        for (int b = t; b < N; b += BS) o[b] = Z[r * ZS + b];
    }
}

// ---------------- ck1/ck2: split column pass (proven structure; R5/R7: do NOT fuse) ----
template<int N1, int N2, int SPLIT, int BS>
__global__ __launch_bounds__(BS) void ck1(
    const float2* __restrict__ in, const float2* __restrict__ FT, float2* __restrict__ out)
{
    constexpr int N = N1 * N2;
    constexpr int NC = N / SPLIT;
    const float2* W1 = FT;
    const float2* TW = FT + N1 * N1 + N2 * N2;
    const int g = blockIdx.x / SPLIT, half = blockIdx.x % SPLIT;
    const int n2 = blockIdx.y, t = threadIdx.x;
    if (2 * t >= NC) return;
    const int b0 = 2 * t + half * NC;
    const float2* I = in + (size_t)g * N * N;
    float2 acc[N1][2];
#pragma unroll
    for (int k1 = 0; k1 < N1; ++k1) { acc[k1][0] = make_float2(0.f, 0.f); acc[k1][1] = make_float2(0.f, 0.f); }
    for (int n1 = 0; n1 < N1; ++n1) {
        float4 v = *reinterpret_cast<const float4*>(&I[(size_t)(n1 * N2 + n2) * N + b0]);
        float2 v0 = make_float2(v.x, v.y), v1 = make_float2(v.z, v.w);
#pragma unroll
        for (int k1 = 0; k1 < N1; ++k1) {
            float2 w = W1[n1 * N1 + k1];
            cmac(acc[k1][0], v0, w);
            cmac(acc[k1][1], v1, w);
        }
    }
#pragma unroll
    for (int k1 = 0; k1 < N1; ++k1) {
        float2 tw = TW[n2 * N1 + k1];
        float2 a0, a1;
        a0.x = acc[k1][0].x * tw.x - acc[k1][0].y * tw.y;
        a0.y = acc[k1][0].x * tw.y + acc[k1][0].y * tw.x;
        a1.x = acc[k1][1].x * tw.x - acc[k1][1].y * tw.y;
        a1.y = acc[k1][1].x * tw.y + acc[k1][1].y * tw.x;
        *reinterpret_cast<float4*>(&out[((size_t)g * N + (k1 * N2 + n2)) * N + b0]) =
            make_float4(a0.x, a0.y, a1.x, a1.y);
    }
}

template<int N1, int N2, int SPLIT, int MODE, int BS>
__global__ __launch_bounds__(BS) void ck2(
    const float2* __restrict__ in, const float2* __restrict__ FT,
    float2* __restrict__ outc, float* __restrict__ outr)
{
    constexpr int N = N1 * N2;
    constexpr int NC = N / SPLIT;
    const float2* W2 = FT + N1 * N1;
    const int g = blockIdx.x / SPLIT, half = blockIdx.x % SPLIT;
    const int k1 = blockIdx.y, t = threadIdx.x;
    if (2 * t >= NC) return;
    const int b0 = 2 * t + half * NC;
    const float2* I = in + (size_t)g * N * N;
    float2 acc[N2][2];
#pragma unroll
    for (int k2 = 0; k2 < N2; ++k2) { acc[k2][0] = make_float2(0.f, 0.f); acc[k2][1] = make_float2(0.f, 0.f); }
    for (int n2 = 0; n2 < N2; ++n2) {
        float4 v = *reinterpret_cast<const float4*>(&I[(size_t)(k1 * N2 + n2) * N + b0]);
        float2 v0 = make_float2(v.x, v.y), v1 = make_float2(v.z, v.w);
#pragma unroll
        for (int k2 = 0; k2 < N2; ++k2) {
            float2 w = W2[n2 * N2 + k2];
            cmac(acc[k2][0], v0, w);
            cmac(acc[k2][1], v1, w);
        }
    }
    if (MODE == 0) {
#pragma unroll
        for (int k2 = 0; k2 < N2; ++k2)
            *reinterpret_cast<float4*>(&outc[((size_t)g * N + (k1 + N1 * k2)) * N + b0]) =
                make_float4(acc[k2][0].x, acc[k2][0].y, acc[k2][1].x, acc[k2][1].y);
    } else {
#pragma unroll
        for (int k2 = 0; k2 < N2; ++k2) {
            size_t o = ((size_t)g * N + (k1 + N1 * k2)) * N + b0;
            outr[o]     = sqrtf(acc[k2][0].x * acc[k2][0].x + acc[k2][0].y * acc[k2][0].y);
            outr[o + 1] = sqrtf(acc[k2][1].x * acc[k2][1].x + acc[k2][1].y * acc[k2][1].y);
        }
    }
}

// ---------------- 56-res dense kernels (R6-proven) ----------------
template<int NOUT, int FOLD, int TA, int BS>
__global__ __launch_bounds__(BS) void rowpass_c(
    const float2* __restrict__ inBase, int inShift,
    const float* __restrict__ fltBase, int fltMask,
    const float2* __restrict__ W, float2* __restrict__ out)
{
    constexpr int NIN = NOUT * FOLD;
    __shared__ float2 Z[TA * NOUT];
    const int g = blockIdx.x;
    const int a0 = blockIdx.y * TA;
    const float2* in = inBase + (size_t)(g >> inShift) * (NIN * NIN);
    const float* flt = fltBase + (size_t)(g & fltMask) * (NIN * NIN);
    const int t = threadIdx.x;
    const float s = 1.0f / (float)(FOLD * FOLD);
    for (int r = 0; r < TA; ++r) {
        const int a = a0 + r;
        for (int b = t; b < NOUT; b += BS) {
            float re = 0.f, im = 0.f;
#pragma unroll
            for (int i = 0; i < FOLD; ++i)
#pragma unroll
                for (int j = 0; j < FOLD; ++j) {
                    const int idx = (a + NOUT * i) * NIN + (b + NOUT * j);
                    float2 v = in[idx];
                    float f = flt[idx];
                    re += v.x * f; im += v.y * f;
                }
            Z[r * NOUT + b] = make_float2(re * s, im * s);
        }
    }
    __syncthreads();
    const int k0 = 2 * t;
    if (k0 < NOUT) {
        float2 acc[TA][2];
#pragma unroll
        for (int r = 0; r < TA; ++r) {
            acc[r][0] = make_float2(0.f, 0.f);
            acc[r][1] = make_float2(0.f, 0.f);
        }
        for (int b = 0; b < NOUT; ++b) {
            float4 w = *reinterpret_cast<const float4*>(&W[b * NOUT + k0]);
#pragma unroll
            for (int r = 0; r < TA; ++r) {
                float2 z = Z[r * NOUT + b];
                acc[r][0].x += z.x * w.x - z.y * w.y;
                acc[r][0].y += z.x * w.y + z.y * w.x;
                acc[r][1].x += z.x * w.z - z.y * w.w;
                acc[r][1].y += z.x * w.w + z.y * w.z;
            }
        }
        float2* o = out + ((size_t)g * NOUT + a0) * NOUT + k0;
#pragma unroll
        for (int r = 0; r < TA; ++r)
            *reinterpret_cast<float4*>(&o[(size_t)r * NOUT]) =
                make_float4(acc[r][0].x, acc[r][0].y, acc[r][1].x, acc[r][1].y);
    }
}

template<int N, int TK, int BS>
__global__ __launch_bounds__(BS) void colpass_max(
    const float2* __restrict__ in, const float2* __restrict__ W,
    unsigned* __restrict__ gk, int slotBase, int slotShift, int slotMask)
{
    __shared__ float2 Wl[N * TK];
    const int g = blockIdx.x;
    const int k0 = blockIdx.y * TK;
    const float2* I = in + (size_t)g * (N * N);
    const int t = threadIdx.x;
    for (int idx = t; idx < N * TK; idx += BS) {
        int a = idx / TK, kt = idx % TK;
        Wl[idx] = W[a * N + k0 + kt];
    }
    __syncthreads();
    const int b0 = 2 * t;
    float m = -INFINITY;
    if (b0 < N) {
        float2 acc[TK][2];
#pragma unroll
        for (int kt = 0; kt < TK; ++kt) {
            acc[kt][0] = make_float2(0.f, 0.f);
            acc[kt][1] = make_float2(0.f, 0.f);
        }
        for (int a = 0; a < N; ++a) {
            float4 v = *reinterpret_cast<const float4*>(&I[(size_t)a * N + b0]);
#pragma unroll
            for (int kt = 0; kt < TK; ++kt) {
                float2 w = Wl[a * TK + kt];
                acc[kt][0].x += w.x * v.x - w.y * v.y;
                acc[kt][1].x += w.x * v.z - w.y * v.w;
            }
        }
#pragma unroll
        for (int kt = 0; kt < TK; ++kt)
            m = fmaxf(m, fmaxf(acc[kt][0].x, acc[kt][1].x));
    }
    for (int off = 32; off > 0; off >>= 1)
        m = fmaxf(m, __shfl_down(m, off, 64));
    if (t == 0) {
        int slot = slotBase + ((g >> slotShift) * 81) + (g & slotMask);
        atomicMax(&gk[slot], fkey(m));
    }
}

// ---------------- classifier head ----------------
__global__ void k_linear(const unsigned* __restrict__ gk, const float* __restrict__ Wl,
                         const float* __restrict__ bl, float* __restrict__ out)
{
    int i = blockIdx.x * blockDim.x + threadIdx.x;
    if (i >= 16 * 1000) return;
    int b = i / 1000, o = i % 1000;
    float s = bl[o];
    for (int f = 0; f < 243; ++f)
        s += funkey(gk[b * 243 + f]) * Wl[o * 243 + f];
    out[i] = s;
}

// ---------------- launch ----------------
extern "C" void kernel_launch(void* const* d_in, const int* in_sizes, int n_in,
                              void* d_out, int out_size, void* d_ws, size_t ws_size,
                              hipStream_t stream)
{
    const float* x  = (const float*)d_in[0];
    const float* Wl = (const float*)d_in[1];
    const float* bl = (const float*)d_in[2];
    float* out = (float*)d_out;
    float* ws = (float*)d_ws;

    float2* FT224F = (float2*)(ws + OFF_FT224F);
    float2* FT224I = (float2*)(ws + OFF_FT224I);
    float2* FT112F = (float2*)(ws + OFF_FT112F);
    float2* FT112I = (float2*)(ws + OFF_FT112I);
    float2* F56I  = (float2*)(ws + OFF_F56I);
    float* PSI0 = ws + OFF_PSI;
    float* PSI1 = ws + OFF_PSI + 8 * IMG224;
    float* PHI0 = ws + OFF_PHI0;
    float* PHI1 = ws + OFF_PHI1;
    unsigned* GK = (unsigned*)(ws + OFF_GK);
    float2* XH  = (float2*)(ws + OFF_XH);
    float* A0  = ws + OFF_POOL;          // 9633792 floats
    float* A1  = A0 + 9633792;           // 9633792
    float* A23 = A1 + 9633792;           // 9633792

    // tables
    k_fact<<<4, 256, 0, stream>>>(FT224F, 16, 14, -1.0, 1.0);
    k_fact<<<4, 256, 0, stream>>>(FT224I, 16, 14,  1.0, 1.0 / 224.0);
    k_fact<<<4, 256, 0, stream>>>(FT112F, 16, 7,  -1.0, 1.0);
    k_fact<<<4, 256, 0, stream>>>(FT112I, 16, 7,   1.0, 1.0 / 112.0);
    k_dft<<<(56*56 + 255) / 256, 256, 0, stream>>>(F56I, 56, 1.0, 1.0 / 56.0);
    k_psi<<<(16 * IMG224 + 255) / 256, 256, 0, stream>>>(ws + OFF_PSI);
    k_phi<<<(IMG224 + IMG112 + 255) / 256, 256, 0, stream>>>(PHI0, PHI1);
    k_zero<<<(3888 + 255) / 256, 256, 0, stream>>>(GK, 3888);

    // ---- fft2(x) -> XH ----
    rk<16, 14, 8, 1, 128, true><<<dim3(48, 28), 128, 0, stream>>>(x, 0, nullptr, 0, FT224F, (float2*)A0, 0, 0, 0);
    ck1<16, 14, 2, 64><<<dim3(96, 14), 64, 0, stream>>>((float2*)A0, FT224F, (float2*)A1);
    ck2<16, 14, 2, 0, 64><<<dim3(96, 16), 64, 0, stream>>>((float2*)A1, FT224F, XH, nullptr);

    // ---- s0 -> GK slot img*81+0 ----
    rowpass_c<56, 4, 8, 64><<<dim3(48, 7), 64, 0, stream>>>(XH, 0, PHI0, 0, F56I, (float2*)A1);
    colpass_max<56, 8, 64><<<dim3(48, 7), 64, 0, stream>>>((float2*)A1, F56I, GK, 0, 0, 0);

    // ---- pair-batched first order j1=0 (+ second order); g = img*2 + lc, l1 = 2c+lc ----
    for (int c = 0; c < 4; ++c) {
        // A: ifft rows of xh*psi0[l1] -> A0 (96 groups)
        rk<16, 14, 8, 1, 128, false><<<dim3(96, 28), 128, 0, stream>>>(
            XH, 1, PSI0 + (size_t)(2 * c) * IMG224, 1, FT224I, (float2*)A0, 0, 0, 0);
        // B: ifft cols + |.| -> A23 (real u1)
        ck1<16, 14, 2, 64><<<dim3(192, 14), 64, 0, stream>>>((float2*)A0, FT224I, (float2*)A1);
        ck2<16, 14, 2, 1, 64><<<dim3(192, 16), 64, 0, stream>>>((float2*)A1, FT224I, nullptr, A23);
        // C: fft rows of u1 (real) -> A0
        rk<16, 14, 8, 1, 128, true><<<dim3(96, 28), 128, 0, stream>>>(A23, 0, nullptr, 0, FT224F, (float2*)A0, 0, 0, 0);
        // D: fft cols -> V1 (A0)
        ck1<16, 14, 2, 64><<<dim3(192, 14), 64, 0, stream>>>((float2*)A0, FT224F, (float2*)A1);
        ck2<16, 14, 2, 0, 64><<<dim3(192, 16), 64, 0, stream>>>((float2*)A1, FT224F, (float2*)A0, nullptr);
        // E: s1 -> GK slot img*81 + 1 + 2c + lc
        rowpass_c<56, 4, 8, 64><<<dim3(96, 7), 64, 0, stream>>>((float2*)A0, 0, PHI0, 0, F56I, (float2*)A1);
        colpass_max<56, 8, 64><<<dim3(96, 7), 64, 0, stream>>>((float2*)A1, F56I, GK, 1 + 2 * c, 1, 1);
        // second order per l1 in pair (V1 stays live in A0)
        for (int lc = 0; lc < 2; ++lc) {
            int l1 = 2 * c + lc;
            // F: ifft112 rows of fold(V1*psi1[l2],2) [XCD swizzle] -> A1
            rk<16, 7, 16, 2, 128, false><<<dim3(384, 7), 128, 0, stream>>>(
                (float2*)A0, 0, PSI1, 7, FT112I, (float2*)A1, 48, 2, lc);
            // G: ifft112 cols + |.| : A1 -> A23 (stage1) -> A1 (real u2)
            ck1<16, 7, 1, 64><<<dim3(384, 7), 64, 0, stream>>>((float2*)A1, FT112I, (float2*)A23);
            ck2<16, 7, 1, 1, 64><<<dim3(384, 16), 64, 0, stream>>>((float2*)A23, FT112I, nullptr, A1);
            // H: fft112 rows of u2 (real) -> A23
            rk<16, 7, 16, 1, 128, true><<<dim3(384, 7), 128, 0, stream>>>(A1, 0, nullptr, 0, FT112F, (float2*)A23, 0, 0, 0);
            // I: fft112 cols: A23 -> A1 (stage1) -> A23 (u2h)
            ck1<16, 7, 1, 64><<<dim3(384, 7), 64, 0, stream>>>((float2*)A23, FT112F, (float2*)A1);
            ck2<16, 7, 1, 0, 64><<<dim3(384, 16), 64, 0, stream>>>((float2*)A1, FT112F, (float2*)A23, nullptr);
            // JK: s2 -> GK slot img*81 + 17 + 8*l1 + l2
            rowpass_c<56, 2, 8, 64><<<dim3(384, 7), 64, 0, stream>>>((float2*)A23, 0, PHI1, 0, F56I, (float2*)A1);
            colpass_max<56, 8, 64><<<dim3(384, 7), 64, 0, stream>>>((float2*)A1, F56I, GK, 17 + 8 * l1, 3, 7);
        }
    }

    // ---- first order j1=1 (8 orientations, g = img*8+l) ----
    rk<16, 7, 16, 2, 128, false><<<dim3(384, 7), 128, 0, stream>>>(XH, 0, PSI1, 7, FT112I, (float2*)A1, 48, 1, 0);
    ck1<16, 7, 1, 64><<<dim3(384, 7), 64, 0, stream>>>((float2*)A1, FT112I, (float2*)A23);
    ck2<16, 7, 1, 1, 64><<<dim3(384, 16), 64, 0, stream>>>((float2*)A23, FT112I, nullptr, A1);
    rk<16, 7, 16, 1, 128, true><<<dim3(384, 7), 128, 0, stream>>>(A1, 0, nullptr, 0, FT112F, (float2*)A23, 0, 0, 0);
    ck1<16, 7, 1, 64><<<dim3(384, 7), 64, 0, stream>>>((float2*)A23, FT112F, (float2*)A1);
    ck2<16, 7, 1, 0, 64><<<dim3(384, 16), 64, 0, stream>>>((float2*)A1, FT112F, (float2*)A23, nullptr);
    rowpass_c<56, 2, 8, 64><<<dim3(384, 7), 64, 0, stream>>>((float2*)A23, 0, PHI1, 0, F56I, (float2*)A1);
    colpass_max<56, 8, 64><<<dim3(384, 7), 64, 0, stream>>>((float2*)A1, F56I, GK, 9, 3, 7);

    // head
    k_linear<<<(16000 + 255) / 256, 256, 0, stream>>>(GK, Wl, bl, out);
}